// Round 10
// baseline (195.901 us; speedup 1.0000x reference)
//
#include <hip/hip_runtime.h>

#define N_NODES 100000
#define N_EDGES 800000
#define IN_DIM 128
#define HID 64
#define OUT_DIM 7
#define CAP 32                            // padded-CSR row = exactly one 128-B line
#define NGROUP 8                          // dst-slice groups (locality beats fetch)
#define DSLICE (N_NODES / NGROUP)         // 12500
#define SUBBLK 390

typedef __bf16 vbf8 __attribute__((ext_vector_type(8)));
typedef float  vf4  __attribute__((ext_vector_type(4)));

#define GEMM_BLKS ((N_NODES / 16 + 3) / 4)     // 1563
#define FILL_BLKS (NGROUP * SUBBLK)            // 3120
#define SWZ2_BLKS 16
#define PH1_BLKS (GEMM_BLKS + FILL_BLKS + SWZ2_BLKS + 1)

// ---- W swizzle (bf16 fragment order for 16x16x32 MFMA B-operand) ----
__device__ __forceinline__ void wswz_body(int idx, const float* __restrict__ W,
                                          __bf16* __restrict__ out) {
    int j  = idx & 7;
    int l  = (idx >> 3) & 63;
    int nt = (idx >> 9) & 3;
    int ks = idx >> 11;
    int k  = ks * 32 + ((l >> 4) << 3) + j;
    int n  = nt * 16 + (l & 15);
    out[idx] = (__bf16)W[k * 64 + n];
}

// ---- GEMM layer 1: W1 staged block-cooperatively into LDS in fragment order ----
__device__ __forceinline__ void gemm1_body(int g, int tid, const float* __restrict__ X,
                                           const __bf16* __restrict__ Wlds,
                                           __bf16* __restrict__ Hb) {
    constexpr int K = IN_DIM, KS = K / 32;   // 4
    const int lane = tid & 63;
    const int w = g * 4 + (tid >> 6);
    if (w >= N_NODES / 16) return;
    const int r0 = w * 16;
    const int m = lane & 15;
    const int quad = lane >> 4;

    vbf8 bfrag[KS][4];
    const vbf8* wp = (const vbf8*)Wlds;
    #pragma unroll
    for (int ks = 0; ks < KS; ++ks)
        #pragma unroll
        for (int nt = 0; nt < 4; ++nt)
            bfrag[ks][nt] = wp[(ks * 4 + nt) * 64 + lane];

    vf4 acc[4] = {};
    #pragma unroll
    for (int ks = 0; ks < KS; ++ks) {
        const float* xp = X + (size_t)(r0 + m) * K + ks * 32 + quad * 8;
        float4 f0 = *(const float4*)xp;
        float4 f1 = *(const float4*)(xp + 4);
        vbf8 a;
        a[0] = (__bf16)f0.x; a[1] = (__bf16)f0.y; a[2] = (__bf16)f0.z; a[3] = (__bf16)f0.w;
        a[4] = (__bf16)f1.x; a[5] = (__bf16)f1.y; a[6] = (__bf16)f1.z; a[7] = (__bf16)f1.w;
        #pragma unroll
        for (int nt = 0; nt < 4; ++nt)
            acc[nt] = __builtin_amdgcn_mfma_f32_16x16x32_bf16(a, bfrag[ks][nt], acc[nt], 0, 0, 0);
    }
    #pragma unroll
    for (int nt = 0; nt < 4; ++nt)
        #pragma unroll
        for (int r = 0; r < 4; ++r)
            Hb[(size_t)(r0 + quad * 4 + r) * 64 + nt * 16 + m] = (__bf16)acc[nt][r];
}

// ---- partitioned CSR build (grid-stride; atomics batched) ----
__device__ __forceinline__ void fill_body(int bb, int tid, const int* __restrict__ ei,
                                          int* __restrict__ cnt, int* __restrict__ csr) {
    int group = bb & 7, sub = bb >> 3;
    int lo = group * DSLICE;
    const int4* dst4 = (const int4*)(ei + N_EDGES);
    const int4* src4 = (const int4*)ei;
    for (int e4 = sub * 256 + tid; e4 < N_EDGES / 4; e4 += SUBBLK * 256) {
        int4 d4 = dst4[e4];
        bool m0 = (unsigned)(d4.x - lo) < (unsigned)DSLICE;
        bool m1 = (unsigned)(d4.y - lo) < (unsigned)DSLICE;
        bool m2 = (unsigned)(d4.z - lo) < (unsigned)DSLICE;
        bool m3 = (unsigned)(d4.w - lo) < (unsigned)DSLICE;
        if (!(m0 | m1 | m2 | m3)) continue;
        int4 s4 = src4[e4];
        int p0 = 0, p1 = 0, p2 = 0, p3 = 0;
        if (m0) p0 = atomicAdd(&cnt[d4.x], 1);
        if (m1) p1 = atomicAdd(&cnt[d4.y], 1);
        if (m2) p2 = atomicAdd(&cnt[d4.z], 1);
        if (m3) p3 = atomicAdd(&cnt[d4.w], 1);
        if (m0 && p0 < CAP) csr[(size_t)d4.x * CAP + p0] = s4.x;
        if (m1 && p1 < CAP) csr[(size_t)d4.y * CAP + p1] = s4.y;
        if (m2 && p2 < CAP) csr[(size_t)d4.z * CAP + p2] = s4.z;
        if (m3 && p3 < CAP) csr[(size_t)d4.w * CAP + p3] = s4.w;
    }
}

// ======== phase 1: gemm1 (W1->LDS swizzle) | CSR fill | Wz2 swizzle | dead rows ========
__global__ __launch_bounds__(256)
void k_phase1(const int* __restrict__ ei, int* __restrict__ cnt, int* __restrict__ csr,
              const float* __restrict__ X, const float* __restrict__ W1,
              const float* __restrict__ W2, __bf16* __restrict__ Wz2,
              __bf16* __restrict__ HbA, __bf16* __restrict__ HbB,
              float* __restrict__ S) {
    __shared__ __bf16 wlds[IN_DIM * 64];     // 16 KB
    int b = blockIdx.x;
    int t = threadIdx.x;
    if (b < GEMM_BLKS) {
        // cooperative swizzle-stage of W1; lane-consecutive 16-B writes: conflict-free
        #pragma unroll
        for (int c = 0; c < 4; ++c) {
            int l  = t & 63;
            int nt = t >> 6;
            int krow = c * 32 + ((l >> 4) << 3);
            int n = nt * 16 + (l & 15);
            vbf8 o;
            #pragma unroll
            for (int j = 0; j < 8; ++j) o[j] = (__bf16)W1[(krow + j) * 64 + n];
            *(vbf8*)&wlds[(c * 256 + t) * 8] = o;
        }
        __syncthreads();
        gemm1_body(b, t, X, wlds, HbA);
        return;
    }
    b -= GEMM_BLKS;
    if (b < FILL_BLKS) { fill_body(b, t, ei, cnt, csr); return; }
    b -= FILL_BLKS;
    if (b < SWZ2_BLKS) { wswz_body(b * 256 + t, W2, Wz2); return; }
    // zero dead-slot rows (row N): consumed by later kernels only
    if (t < 32)       ((unsigned*)(HbA + (size_t)N_NODES * 64))[t] = 0u;
    else if (t < 64)  ((unsigned*)(HbB + (size_t)N_NODES * 64))[t - 32] = 0u;
    else if (t < 71)  S[(size_t)N_NODES * 7 + (t - 64)] = 0.0f;
}

// ======== phase 2: gather #1 (hoisted rows + hoisted cnt, fused dinv tree) + gemm2 ========
// (256,4): cap 128 VGPR, 16 waves/CU — 2x TLP vs (256,2) for latency hiding.
__global__ __launch_bounds__(256, 4)
void k_g64gemm2(const int* __restrict__ cnt, const int* __restrict__ csr,
                const float* __restrict__ bias, const __bf16* __restrict__ Hs,
                const __bf16* __restrict__ Wz2, __bf16* __restrict__ HbB) {
    __shared__ __bf16 tl[32][72];            // +8 bf16 pad: conflict-free MFMA reads
    const int tid = threadIdx.x;
    const int nl = tid >> 3;
    const int q  = tid & 7;
    const int node = blockIdx.x * 32 + nl;   // grid exact: 3125*32 = 100000

    int deg = cnt[node];
    int end = deg < CAP ? deg : CAP;
    float dd = rsqrtf((float)deg + 1.0f);

    const int4* row4 = (const int4*)(csr + (size_t)node * CAP);
    int4 qa = row4[0], qb = row4[1], qc = row4[2], qd = row4[3];
    int srcs[16] = {qa.x, qa.y, qa.z, qa.w, qb.x, qb.y, qb.z, qb.w,
                    qc.x, qc.y, qc.z, qc.w, qd.x, qd.y, qd.z, qd.w};
    #pragma unroll
    for (int t = 0; t < 16; ++t)
        srcs[t] = (t < end) ? srcs[t] : N_NODES;     // row N zeros, cnt[N]=0
    vbf8 v[16];
    #pragma unroll
    for (int t = 0; t < 16; ++t)
        v[t] = *(const vbf8*)(Hs + (size_t)srcs[t] * 64 + q * 8);
    int c16[16];
    #pragma unroll
    for (int t = 0; t < 16; ++t)
        c16[t] = cnt[srcs[t]];
    vbf8 h8 = *(const vbf8*)(Hs + (size_t)node * 64 + q * 8);

    float ds[16];
    #pragma unroll
    for (int t = 0; t < 16; ++t)
        ds[t] = rsqrtf((float)c16[t] + 1.0f);
    float a4[4][8];
    #pragma unroll
    for (int g = 0; g < 4; ++g)
        #pragma unroll
        for (int u = 0; u < 8; ++u)
            a4[g][u] = fmaf((float)v[g * 4][u],     ds[g * 4],
                       fmaf((float)v[g * 4 + 1][u], ds[g * 4 + 1],
                       fmaf((float)v[g * 4 + 2][u], ds[g * 4 + 2],
                            (float)v[g * 4 + 3][u] * ds[g * 4 + 3])));
    float acc[8];
    #pragma unroll
    for (int u = 0; u < 8; ++u)
        acc[u] = ((a4[0][u] + a4[1][u]) + (a4[2][u] + a4[3][u])) + (float)h8[u] * dd;
    for (int j = 16; j < end; ++j) {          // rare tail (deg>16)
        int s = (csr + (size_t)node * CAP)[j];
        float dsj = rsqrtf((float)cnt[s] + 1.0f);
        vbf8 w = *(const vbf8*)(Hs + (size_t)s * 64 + q * 8);
        #pragma unroll
        for (int u = 0; u < 8; ++u) acc[u] = fmaf((float)w[u], dsj, acc[u]);
    }
    float4 b0 = *(const float4*)(bias + q * 8);
    float4 b1 = *(const float4*)(bias + q * 8 + 4);
    float bb[8] = {b0.x, b0.y, b0.z, b0.w, b1.x, b1.y, b1.z, b1.w};
    vbf8 o;
    #pragma unroll
    for (int t = 0; t < 8; ++t) o[t] = (__bf16)fmaxf(fmaf(acc[t], dd, bb[t]), 0.f);
    *(vbf8*)&tl[nl][q * 8] = o;
    __syncthreads();

    // ---- gemm2: wave -> (tile, nt-pair) ----
    const int wave = tid >> 6;
    const int lane = tid & 63;
    const int m = lane & 15;
    const int quad = lane >> 4;
    const int tile = wave >> 1;
    const int nt0 = (wave & 1) * 2;

    vbf8 bfrag[2][2];
    const vbf8* wp = (const vbf8*)Wz2;
    #pragma unroll
    for (int ks = 0; ks < 2; ++ks)
        #pragma unroll
        for (int i = 0; i < 2; ++i)
            bfrag[ks][i] = wp[(ks * 4 + nt0 + i) * 64 + lane];

    vf4 acc2[2] = {};
    #pragma unroll
    for (int ks = 0; ks < 2; ++ks) {
        vbf8 a = *(const vbf8*)&tl[tile * 16 + m][ks * 32 + quad * 8];
        #pragma unroll
        for (int i = 0; i < 2; ++i)
            acc2[i] = __builtin_amdgcn_mfma_f32_16x16x32_bf16(a, bfrag[ks][i], acc2[i], 0, 0, 0);
    }
    const int gr0 = blockIdx.x * 32 + tile * 16;
    float dv[4];
    #pragma unroll
    for (int r = 0; r < 4; ++r)
        dv[r] = rsqrtf((float)cnt[gr0 + quad * 4 + r] + 1.0f);
    #pragma unroll
    for (int i = 0; i < 2; ++i)
        #pragma unroll
        for (int r = 0; r < 4; ++r)
            HbB[(size_t)(gr0 + quad * 4 + r) * 64 + (nt0 + i) * 16 + m] =
                (__bf16)(acc2[i][r] * dv[r]);
}

// ====== gather #2 (pure-sum, hoisted+tree; HbB pre-scaled) + fused W3 projection ======
__global__ __launch_bounds__(256, 4)
void k_gather64m(const int* __restrict__ cnt, const int* __restrict__ csr,
                 const float* __restrict__ bias, const __bf16* __restrict__ Hs,
                 const float* __restrict__ W3, float* __restrict__ S) {
    int node = blockIdx.x * 32 + (threadIdx.x >> 3);
    int q = threadIdx.x & 7;
    if (node >= N_NODES) return;
    int deg = cnt[node];
    int end = deg < CAP ? deg : CAP;
    float dd = rsqrtf((float)deg + 1.0f);

    const int4* row4 = (const int4*)(csr + (size_t)node * CAP);
    int4 qa = row4[0], qb = row4[1], qc = row4[2], qd = row4[3];
    int srcs[16] = {qa.x, qa.y, qa.z, qa.w, qb.x, qb.y, qb.z, qb.w,
                    qc.x, qc.y, qc.z, qc.w, qd.x, qd.y, qd.z, qd.w};
    vbf8 v[16];
    #pragma unroll
    for (int t = 0; t < 16; ++t) {
        int s = (t < end) ? srcs[t] : N_NODES;
        v[t] = *(const vbf8*)(Hs + (size_t)s * 64 + q * 8);
    }
    vbf8 h8 = *(const vbf8*)(Hs + (size_t)node * 64 + q * 8);
    float a4[4][8];
    #pragma unroll
    for (int g = 0; g < 4; ++g)
        #pragma unroll
        for (int u = 0; u < 8; ++u)
            a4[g][u] = ((float)v[g * 4][u] + (float)v[g * 4 + 1][u])
                     + ((float)v[g * 4 + 2][u] + (float)v[g * 4 + 3][u]);
    float acc[8];
    #pragma unroll
    for (int u = 0; u < 8; ++u)
        acc[u] = ((a4[0][u] + a4[1][u]) + (a4[2][u] + a4[3][u])) + (float)h8[u];
    for (int j = 16; j < end; ++j) {
        int s = (csr + (size_t)node * CAP)[j];
        vbf8 w = *(const vbf8*)(Hs + (size_t)s * 64 + q * 8);
        #pragma unroll
        for (int u = 0; u < 8; ++u) acc[u] += (float)w[u];
    }

    float4 b0 = *(const float4*)(bias + q * 8);
    float4 b1 = *(const float4*)(bias + q * 8 + 4);
    float bb[8] = {b0.x, b0.y, b0.z, b0.w, b1.x, b1.y, b1.z, b1.w};
    float p[7] = {};
    #pragma unroll
    for (int t = 0; t < 8; ++t) {
        float r = fmaxf(fmaf(acc[t], dd, bb[t]), 0.f);
        #pragma unroll
        for (int j = 0; j < 7; ++j)
            p[j] = fmaf(r, W3[(q * 8 + t) * 7 + j], p[j]);
    }
    #pragma unroll
    for (int msk = 1; msk < 8; msk <<= 1)
        #pragma unroll
        for (int j = 0; j < 7; ++j)
            p[j] += __shfl_xor(p[j], msk, 8);
    if (q < 7) {
        float v2 = p[0];
        if (q == 1) v2 = p[1]; else if (q == 2) v2 = p[2]; else if (q == 3) v2 = p[3];
        else if (q == 4) v2 = p[4]; else if (q == 5) v2 = p[5]; else if (q == 6) v2 = p[6];
        S[(size_t)node * 7 + q] = v2 * dd;        // pre-scale by own dinv
    }
}

// ================= final gather (pure-sum, hoisted+tree; S pre-scaled) =================
__global__ __launch_bounds__(256)
void k_gather7(const int* __restrict__ cnt, const int* __restrict__ csr,
               const float* __restrict__ S, const float* __restrict__ b3,
               float* __restrict__ Out) {
    int node = blockIdx.x * 32 + (threadIdx.x >> 3);
    int j7 = threadIdx.x & 7;
    if (node >= N_NODES || j7 >= 7) return;
    int deg = cnt[node];
    int end = deg < CAP ? deg : CAP;
    float dd = rsqrtf((float)deg + 1.0f);
    const int4* row4 = (const int4*)(csr + (size_t)node * CAP);
    int4 qa = row4[0], qb = row4[1], qc = row4[2], qd = row4[3];
    int srcs[16] = {qa.x, qa.y, qa.z, qa.w, qb.x, qb.y, qb.z, qb.w,
                    qc.x, qc.y, qc.z, qc.w, qd.x, qd.y, qd.z, qd.w};
    float v[16];
    #pragma unroll
    for (int t = 0; t < 16; ++t) {
        int s = (t < end) ? srcs[t] : N_NODES;   // row N is zeros
        v[t] = S[(size_t)s * 7 + j7];
    }
    float self = S[(size_t)node * 7 + j7];
    float acc = (((v[0] + v[1]) + (v[2] + v[3])) + ((v[4] + v[5]) + (v[6] + v[7])))
              + (((v[8] + v[9]) + (v[10] + v[11])) + ((v[12] + v[13]) + (v[14] + v[15])))
              + self;
    for (int j = 16; j < end; ++j) {
        int s = (csr + (size_t)node * CAP)[j];
        acc += S[(size_t)s * 7 + j7];
    }
    Out[(size_t)node * 7 + j7] = fmaf(acc, dd, b3[j7]);
}

static inline size_t align256(size_t x) { return (x + 255) & ~(size_t)255; }

extern "C" void kernel_launch(void* const* d_in, const int* in_sizes, int n_in,
                              void* d_out, int out_size, void* d_ws, size_t ws_size,
                              hipStream_t stream) {
    const float* x  = (const float*)d_in[0];
    const int*   ei = (const int*)d_in[1];
    const float* W1 = (const float*)d_in[2];
    const float* b1 = (const float*)d_in[3];
    const float* W2 = (const float*)d_in[4];
    const float* b2 = (const float*)d_in[5];
    const float* W3 = (const float*)d_in[6];
    const float* b3 = (const float*)d_in[7];
    float* out = (float*)d_out;

    char* wsp = (char*)d_ws;
    int*    cnt  = (int*)wsp;    wsp += align256(sizeof(int) * (N_NODES + 1));
    int*    csr  = (int*)wsp;    wsp += align256(sizeof(int) * (size_t)N_NODES * CAP);
    __bf16* Wz2  = (__bf16*)wsp; wsp += align256(sizeof(__bf16) * HID * 64);
    __bf16* HbA  = (__bf16*)wsp; wsp += align256(sizeof(__bf16) * (size_t)(N_NODES + 1) * 64);
    __bf16* HbB  = (__bf16*)wsp; wsp += align256(sizeof(__bf16) * (size_t)(N_NODES + 1) * 64);
    float*  bufS = (float*)wsp;  wsp += align256(sizeof(float) * (size_t)(N_NODES + 1) * 7);

    hipMemsetAsync(cnt, 0, sizeof(int) * (N_NODES + 1), stream);   // +1: pad slot, dinv=1
    k_phase1<<<PH1_BLKS, 256, 0, stream>>>(ei, cnt, csr, x, W1, W2, Wz2, HbA, HbB, bufS);
    k_g64gemm2<<<N_NODES / 32, 256, 0, stream>>>(cnt, csr, b1, HbA, Wz2, HbB);
    k_gather64m<<<N_NODES / 32, 256, 0, stream>>>(cnt, csr, b2, HbB, W3, bufS);
    k_gather7<<<N_NODES / 32, 256, 0, stream>>>(cnt, csr, bufS, b3, out);
}

// Round 12
// 192.325 us; speedup vs baseline: 1.0186x; 1.0186x over previous
//
#include <hip/hip_runtime.h>

#define N_NODES 100000
#define N_EDGES 800000
#define IN_DIM 128
#define HID 64
#define OUT_DIM 7
#define CAP 32                            // padded-CSR row = exactly one 128-B line
#define NGROUP 8                          // dst-slice groups (locality beats fetch)
#define DSLICE (N_NODES / NGROUP)         // 12500
#define SUBBLK 390

typedef __bf16 vbf8 __attribute__((ext_vector_type(8)));
typedef float  vf4  __attribute__((ext_vector_type(4)));

#define GEMM_BLKS ((N_NODES / 16 + 3) / 4)     // 1563
#define FILL_BLKS (NGROUP * SUBBLK)            // 3120
#define SWZ2_BLKS 16
#define PH1_BLKS (GEMM_BLKS + FILL_BLKS + SWZ2_BLKS + 1)

// ---- W swizzle (bf16 fragment order for 16x16x32 MFMA B-operand) ----
__device__ __forceinline__ void wswz_body(int idx, const float* __restrict__ W,
                                          __bf16* __restrict__ out) {
    int j  = idx & 7;
    int l  = (idx >> 3) & 63;
    int nt = (idx >> 9) & 3;
    int ks = idx >> 11;
    int k  = ks * 32 + ((l >> 4) << 3) + j;
    int n  = nt * 16 + (l & 15);
    out[idx] = (__bf16)W[k * 64 + n];
}

// ---- GEMM layer 1: W1 staged block-cooperatively into LDS in fragment order ----
__device__ __forceinline__ void gemm1_body(int g, int tid, const float* __restrict__ X,
                                           const __bf16* Wlds, __bf16* __restrict__ Hb) {
    constexpr int K = IN_DIM, KS = K / 32;   // 4
    const int lane = tid & 63;
    const int w = g * 4 + (tid >> 6);
    if (w >= N_NODES / 16) return;
    const int r0 = w * 16;
    const int m = lane & 15;
    const int quad = lane >> 4;

    vbf8 bfrag[KS][4];
    const vbf8* wp = (const vbf8*)Wlds;
    #pragma unroll
    for (int ks = 0; ks < KS; ++ks)
        #pragma unroll
        for (int nt = 0; nt < 4; ++nt)
            bfrag[ks][nt] = wp[(ks * 4 + nt) * 64 + lane];

    vf4 acc[4] = {};
    #pragma unroll
    for (int ks = 0; ks < KS; ++ks) {
        const float* xp = X + (size_t)(r0 + m) * K + ks * 32 + quad * 8;
        float4 f0 = *(const float4*)xp;
        float4 f1 = *(const float4*)(xp + 4);
        vbf8 a;
        a[0] = (__bf16)f0.x; a[1] = (__bf16)f0.y; a[2] = (__bf16)f0.z; a[3] = (__bf16)f0.w;
        a[4] = (__bf16)f1.x; a[5] = (__bf16)f1.y; a[6] = (__bf16)f1.z; a[7] = (__bf16)f1.w;
        #pragma unroll
        for (int nt = 0; nt < 4; ++nt)
            acc[nt] = __builtin_amdgcn_mfma_f32_16x16x32_bf16(a, bfrag[ks][nt], acc[nt], 0, 0, 0);
    }
    #pragma unroll
    for (int nt = 0; nt < 4; ++nt)
        #pragma unroll
        for (int r = 0; r < 4; ++r)
            Hb[(size_t)(r0 + quad * 4 + r) * 64 + nt * 16 + m] = (__bf16)acc[nt][r];
}

// ---- partitioned CSR build (grid-stride; atomics batched) ----
__device__ __forceinline__ void fill_body(int bb, int tid, const int* __restrict__ ei,
                                          int* __restrict__ cnt, int* __restrict__ csr) {
    int group = bb & 7, sub = bb >> 3;
    int lo = group * DSLICE;
    const int4* dst4 = (const int4*)(ei + N_EDGES);
    const int4* src4 = (const int4*)ei;
    for (int e4 = sub * 256 + tid; e4 < N_EDGES / 4; e4 += SUBBLK * 256) {
        int4 d4 = dst4[e4];
        bool m0 = (unsigned)(d4.x - lo) < (unsigned)DSLICE;
        bool m1 = (unsigned)(d4.y - lo) < (unsigned)DSLICE;
        bool m2 = (unsigned)(d4.z - lo) < (unsigned)DSLICE;
        bool m3 = (unsigned)(d4.w - lo) < (unsigned)DSLICE;
        if (!(m0 | m1 | m2 | m3)) continue;
        int4 s4 = src4[e4];
        int p0 = 0, p1 = 0, p2 = 0, p3 = 0;
        if (m0) p0 = atomicAdd(&cnt[d4.x], 1);
        if (m1) p1 = atomicAdd(&cnt[d4.y], 1);
        if (m2) p2 = atomicAdd(&cnt[d4.z], 1);
        if (m3) p3 = atomicAdd(&cnt[d4.w], 1);
        if (m0 && p0 < CAP) csr[(size_t)d4.x * CAP + p0] = s4.x;
        if (m1 && p1 < CAP) csr[(size_t)d4.y * CAP + p1] = s4.y;
        if (m2 && p2 < CAP) csr[(size_t)d4.z * CAP + p2] = s4.z;
        if (m3 && p3 < CAP) csr[(size_t)d4.w * CAP + p3] = s4.w;
    }
}

// ======== phase 1: gemm1 (W1->LDS swizzle) | CSR fill | Wz2 swizzle | dead rows ========
__global__ __launch_bounds__(256)
void k_phase1(const int* __restrict__ ei, int* __restrict__ cnt, int* __restrict__ csr,
              const float* __restrict__ X, const float* __restrict__ W1,
              const float* __restrict__ W2, __bf16* __restrict__ Wz2,
              __bf16* __restrict__ HbA, __bf16* __restrict__ HbB,
              float* __restrict__ S) {
    __shared__ __bf16 wlds[IN_DIM * 64];     // 16 KB
    int b = blockIdx.x;
    int t = threadIdx.x;
    if (b < GEMM_BLKS) {
        // cooperative swizzle-stage of W1; lane-consecutive 16-B writes: conflict-free
        #pragma unroll
        for (int c = 0; c < 4; ++c) {
            int l  = t & 63;
            int nt = t >> 6;
            int krow = c * 32 + ((l >> 4) << 3);
            int n = nt * 16 + (l & 15);
            vbf8 o;
            #pragma unroll
            for (int j = 0; j < 8; ++j) o[j] = (__bf16)W1[(krow + j) * 64 + n];
            *(vbf8*)&wlds[(c * 256 + t) * 8] = o;
        }
        __syncthreads();
        gemm1_body(b, t, X, wlds, HbA);
        return;
    }
    b -= GEMM_BLKS;
    if (b < FILL_BLKS) { fill_body(b, t, ei, cnt, csr); return; }
    b -= FILL_BLKS;
    if (b < SWZ2_BLKS) { wswz_body(b * 256 + t, W2, Wz2); return; }
    // zero dead-slot rows (row N): consumed by later kernels only
    if (t < 32)       ((unsigned*)(HbA + (size_t)N_NODES * 64))[t] = 0u;
    else if (t < 64)  ((unsigned*)(HbB + (size_t)N_NODES * 64))[t - 32] = 0u;
    else if (t < 71)  S[(size_t)N_NODES * 7 + (t - 64)] = 0.0f;
}

// ======== phase 2: gather #1 (hoisted rows + hoisted cnt, fused dinv tree) + gemm2 ========
__global__ __launch_bounds__(256, 2)
void k_g64gemm2(const int* __restrict__ cnt, const int* __restrict__ csr,
                const float* __restrict__ bias, const __bf16* __restrict__ Hs,
                const __bf16* __restrict__ Wz2, __bf16* __restrict__ HbB) {
    __shared__ __bf16 tl[32][72];            // +8 bf16 pad: conflict-free MFMA reads
    const int tid = threadIdx.x;
    const int nl = tid >> 3;
    const int q  = tid & 7;
    const int node = blockIdx.x * 32 + nl;   // grid exact: 3125*32 = 100000

    int deg = cnt[node];
    int end = deg < CAP ? deg : CAP;
    float dd = rsqrtf((float)deg + 1.0f);

    const int4* row4 = (const int4*)(csr + (size_t)node * CAP);
    int4 qa = row4[0], qb = row4[1], qc = row4[2], qd = row4[3];
    int srcs[16] = {qa.x, qa.y, qa.z, qa.w, qb.x, qb.y, qb.z, qb.w,
                    qc.x, qc.y, qc.z, qc.w, qd.x, qd.y, qd.z, qd.w};
    #pragma unroll
    for (int t = 0; t < 16; ++t)
        srcs[t] = (t < end) ? srcs[t] : N_NODES;     // row N zeros, cnt[N]=0
    vbf8 v[16];
    #pragma unroll
    for (int t = 0; t < 16; ++t)
        v[t] = *(const vbf8*)(Hs + (size_t)srcs[t] * 64 + q * 8);
    int c16[16];
    #pragma unroll
    for (int t = 0; t < 16; ++t)
        c16[t] = cnt[srcs[t]];
    vbf8 h8 = *(const vbf8*)(Hs + (size_t)node * 64 + q * 8);

    float ds[16];
    #pragma unroll
    for (int t = 0; t < 16; ++t)
        ds[t] = rsqrtf((float)c16[t] + 1.0f);
    float a4[4][8];
    #pragma unroll
    for (int g = 0; g < 4; ++g)
        #pragma unroll
        for (int u = 0; u < 8; ++u)
            a4[g][u] = fmaf((float)v[g * 4][u],     ds[g * 4],
                       fmaf((float)v[g * 4 + 1][u], ds[g * 4 + 1],
                       fmaf((float)v[g * 4 + 2][u], ds[g * 4 + 2],
                            (float)v[g * 4 + 3][u] * ds[g * 4 + 3])));
    float acc[8];
    #pragma unroll
    for (int u = 0; u < 8; ++u)
        acc[u] = ((a4[0][u] + a4[1][u]) + (a4[2][u] + a4[3][u])) + (float)h8[u] * dd;
    for (int j = 16; j < end; ++j) {          // rare tail (deg>16)
        int s = (csr + (size_t)node * CAP)[j];
        float dsj = rsqrtf((float)cnt[s] + 1.0f);
        vbf8 w = *(const vbf8*)(Hs + (size_t)s * 64 + q * 8);
        #pragma unroll
        for (int u = 0; u < 8; ++u) acc[u] = fmaf((float)w[u], dsj, acc[u]);
    }
    float4 b0 = *(const float4*)(bias + q * 8);
    float4 b1 = *(const float4*)(bias + q * 8 + 4);
    float bb[8] = {b0.x, b0.y, b0.z, b0.w, b1.x, b1.y, b1.z, b1.w};
    vbf8 o;
    #pragma unroll
    for (int t = 0; t < 8; ++t) o[t] = (__bf16)fmaxf(fmaf(acc[t], dd, bb[t]), 0.f);
    *(vbf8*)&tl[nl][q * 8] = o;
    __syncthreads();

    // ---- gemm2: wave -> (tile, nt-pair) ----
    const int wave = tid >> 6;
    const int lane = tid & 63;
    const int m = lane & 15;
    const int quad = lane >> 4;
    const int tile = wave >> 1;
    const int nt0 = (wave & 1) * 2;

    vbf8 bfrag[2][2];
    const vbf8* wp = (const vbf8*)Wz2;
    #pragma unroll
    for (int ks = 0; ks < 2; ++ks)
        #pragma unroll
        for (int i = 0; i < 2; ++i)
            bfrag[ks][i] = wp[(ks * 4 + nt0 + i) * 64 + lane];

    vf4 acc2[2] = {};
    #pragma unroll
    for (int ks = 0; ks < 2; ++ks) {
        vbf8 a = *(const vbf8*)&tl[tile * 16 + m][ks * 32 + quad * 8];
        #pragma unroll
        for (int i = 0; i < 2; ++i)
            acc2[i] = __builtin_amdgcn_mfma_f32_16x16x32_bf16(a, bfrag[ks][i], acc2[i], 0, 0, 0);
    }
    const int gr0 = blockIdx.x * 32 + tile * 16;
    float dv[4];
    #pragma unroll
    for (int r = 0; r < 4; ++r)
        dv[r] = rsqrtf((float)cnt[gr0 + quad * 4 + r] + 1.0f);
    #pragma unroll
    for (int i = 0; i < 2; ++i)
        #pragma unroll
        for (int r = 0; r < 4; ++r)
            HbB[(size_t)(gr0 + quad * 4 + r) * 64 + (nt0 + i) * 16 + m] =
                (__bf16)(acc2[i][r] * dv[r]);
}

// ====== gather #2 (pure-sum, hoisted+tree; HbB pre-scaled) + fused W3 projection ======
__global__ __launch_bounds__(256, 2)
void k_gather64m(const int* __restrict__ cnt, const int* __restrict__ csr,
                 const float* __restrict__ bias, const __bf16* __restrict__ Hs,
                 const float* __restrict__ W3, float* __restrict__ S) {
    int node = blockIdx.x * 32 + (threadIdx.x >> 3);
    int q = threadIdx.x & 7;
    if (node >= N_NODES) return;
    int deg = cnt[node];
    int end = deg < CAP ? deg : CAP;
    float dd = rsqrtf((float)deg + 1.0f);

    const int4* row4 = (const int4*)(csr + (size_t)node * CAP);
    int4 qa = row4[0], qb = row4[1], qc = row4[2], qd = row4[3];
    int srcs[16] = {qa.x, qa.y, qa.z, qa.w, qb.x, qb.y, qb.z, qb.w,
                    qc.x, qc.y, qc.z, qc.w, qd.x, qd.y, qd.z, qd.w};
    vbf8 v[16];
    #pragma unroll
    for (int t = 0; t < 16; ++t) {
        int s = (t < end) ? srcs[t] : N_NODES;
        v[t] = *(const vbf8*)(Hs + (size_t)s * 64 + q * 8);
    }
    vbf8 h8 = *(const vbf8*)(Hs + (size_t)node * 64 + q * 8);
    float a4[4][8];
    #pragma unroll
    for (int g = 0; g < 4; ++g)
        #pragma unroll
        for (int u = 0; u < 8; ++u)
            a4[g][u] = ((float)v[g * 4][u] + (float)v[g * 4 + 1][u])
                     + ((float)v[g * 4 + 2][u] + (float)v[g * 4 + 3][u]);
    float acc[8];
    #pragma unroll
    for (int u = 0; u < 8; ++u)
        acc[u] = ((a4[0][u] + a4[1][u]) + (a4[2][u] + a4[3][u])) + (float)h8[u];
    for (int j = 16; j < end; ++j) {
        int s = (csr + (size_t)node * CAP)[j];
        vbf8 w = *(const vbf8*)(Hs + (size_t)s * 64 + q * 8);
        #pragma unroll
        for (int u = 0; u < 8; ++u) acc[u] += (float)w[u];
    }

    float4 b0 = *(const float4*)(bias + q * 8);
    float4 b1 = *(const float4*)(bias + q * 8 + 4);
    float bb[8] = {b0.x, b0.y, b0.z, b0.w, b1.x, b1.y, b1.z, b1.w};
    float p[7] = {};
    #pragma unroll
    for (int t = 0; t < 8; ++t) {
        float r = fmaxf(fmaf(acc[t], dd, bb[t]), 0.f);
        #pragma unroll
        for (int j = 0; j < 7; ++j)
            p[j] = fmaf(r, W3[(q * 8 + t) * 7 + j], p[j]);
    }
    #pragma unroll
    for (int msk = 1; msk < 8; msk <<= 1)
        #pragma unroll
        for (int j = 0; j < 7; ++j)
            p[j] += __shfl_xor(p[j], msk, 8);
    if (q < 7) {
        float v2 = p[0];
        if (q == 1) v2 = p[1]; else if (q == 2) v2 = p[2]; else if (q == 3) v2 = p[3];
        else if (q == 4) v2 = p[4]; else if (q == 5) v2 = p[5]; else if (q == 6) v2 = p[6];
        S[(size_t)node * 7 + q] = v2 * dd;        // pre-scale by own dinv
    }
}

// ================= final gather (pure-sum, hoisted+tree; S pre-scaled) =================
__global__ __launch_bounds__(256)
void k_gather7(const int* __restrict__ cnt, const int* __restrict__ csr,
               const float* __restrict__ S, const float* __restrict__ b3,
               float* __restrict__ Out) {
    int node = blockIdx.x * 32 + (threadIdx.x >> 3);
    int j7 = threadIdx.x & 7;
    if (node >= N_NODES || j7 >= 7) return;
    int deg = cnt[node];
    int end = deg < CAP ? deg : CAP;
    float dd = rsqrtf((float)deg + 1.0f);
    const int4* row4 = (const int4*)(csr + (size_t)node * CAP);
    int4 qa = row4[0], qb = row4[1], qc = row4[2], qd = row4[3];
    int srcs[16] = {qa.x, qa.y, qa.z, qa.w, qb.x, qb.y, qb.z, qb.w,
                    qc.x, qc.y, qc.z, qc.w, qd.x, qd.y, qd.z, qd.w};
    float v[16];
    #pragma unroll
    for (int t = 0; t < 16; ++t) {
        int s = (t < end) ? srcs[t] : N_NODES;   // row N is zeros
        v[t] = S[(size_t)s * 7 + j7];
    }
    float self = S[(size_t)node * 7 + j7];
    float acc = (((v[0] + v[1]) + (v[2] + v[3])) + ((v[4] + v[5]) + (v[6] + v[7])))
              + (((v[8] + v[9]) + (v[10] + v[11])) + ((v[12] + v[13]) + (v[14] + v[15])))
              + self;
    for (int j = 16; j < end; ++j) {
        int s = (csr + (size_t)node * CAP)[j];
        acc += S[(size_t)s * 7 + j7];
    }
    Out[(size_t)node * 7 + j7] = fmaf(acc, dd, b3[j7]);
}

static inline size_t align256(size_t x) { return (x + 255) & ~(size_t)255; }

extern "C" void kernel_launch(void* const* d_in, const int* in_sizes, int n_in,
                              void* d_out, int out_size, void* d_ws, size_t ws_size,
                              hipStream_t stream) {
    const float* x  = (const float*)d_in[0];
    const int*   ei = (const int*)d_in[1];
    const float* W1 = (const float*)d_in[2];
    const float* b1 = (const float*)d_in[3];
    const float* W2 = (const float*)d_in[4];
    const float* b2 = (const float*)d_in[5];
    const float* W3 = (const float*)d_in[6];
    const float* b3 = (const float*)d_in[7];
    float* out = (float*)d_out;

    char* wsp = (char*)d_ws;
    int*    cnt  = (int*)wsp;    wsp += align256(sizeof(int) * (N_NODES + 1));
    int*    csr  = (int*)wsp;    wsp += align256(sizeof(int) * (size_t)N_NODES * CAP);
    __bf16* Wz2  = (__bf16*)wsp; wsp += align256(sizeof(__bf16) * HID * 64);
    __bf16* HbA  = (__bf16*)wsp; wsp += align256(sizeof(__bf16) * (size_t)(N_NODES + 1) * 64);
    __bf16* HbB  = (__bf16*)wsp; wsp += align256(sizeof(__bf16) * (size_t)(N_NODES + 1) * 64);
    float*  bufS = (float*)wsp;  wsp += align256(sizeof(float) * (size_t)(N_NODES + 1) * 7);

    hipMemsetAsync(cnt, 0, sizeof(int) * (N_NODES + 1), stream);   // +1: pad slot, dinv=1
    k_phase1<<<PH1_BLKS, 256, 0, stream>>>(ei, cnt, csr, x, W1, W2, Wz2, HbA, HbB, bufS);
    k_g64gemm2<<<N_NODES / 32, 256, 0, stream>>>(cnt, csr, b1, HbA, Wz2, HbB);
    k_gather64m<<<N_NODES / 32, 256, 0, stream>>>(cnt, csr, b2, HbB, W3, bufS);
    k_gather7<<<N_NODES / 32, 256, 0, stream>>>(cnt, csr, bufS, b3, out);
}